// Round 17
// baseline (352.333 us; speedup 1.0000x reference)
//
#include <hip/hip_runtime.h>
#include <hip/hip_bf16.h>
#include <math.h>

// ---- problem constants ----
// B=128, NC=64, T=1000, SPATIAL_MERGE=32, FILTERS={41,51,61}, NF=192
// FEATURE_DIM = {(3,4),(4,8),(4,16),(7,32),(240,64)}, SUM_SP=1078
// FC_IN = 18528, N_CLASS=4.  Input/output dtype: float32 (confirmed r6/r7).

// workspace layout (float offsets)
#define A_OFF    0         // 32*64
#define BETA_OFF 2048      // 32
#define TBE_OFF  2080      // 192
#define TWE_OFF  2304      // 3*4096, taps zero-padded to 64
#define XS_OFF   14592     // 128*32*1000 (fallback path only after r15)
#define XBP_OFF  4110592   // 128 * 6 tiles * 64*64 packed (end 7,256,320 floats)
#define XT_OFF   7256320   // bf16 Xt [b][192][1024] = 12,582,912 floats worth
#define WS_NEED  ((size_t)19839232 * 4)   // 79.4 MB -> split path; else fused

#define SBN 0.9999950000374997f   // 1/sqrt(1+1e-5)

typedef short short8 __attribute__((ext_vector_type(8)));    // 8 bf16 (4 VGPRs)
typedef float floatx4 __attribute__((ext_vector_type(4)));   // MFMA accumulator

__device__ __forceinline__ unsigned short f2bf(float f) {    // fp32 -> bf16 (RNE)
    unsigned u = __float_as_uint(f);
    u += 0x7FFFu + ((u >> 16) & 1u);
    return (unsigned short)(u >> 16);
}
__device__ __forceinline__ float bf2f(unsigned short h) {
    return __uint_as_float(((unsigned)h) << 16);
}

// ---------------------------------------------------------------------------
// K1: wave-parallel folding (verified r10).
// ---------------------------------------------------------------------------
__global__ __launch_bounds__(256) void prep_kernel(
    const float* __restrict__ sw0, const float* __restrict__ sw1,
    const float* __restrict__ sw2, const float* __restrict__ sw3,
    const float* __restrict__ sw4,
    const float* __restrict__ sb0, const float* __restrict__ sb1,
    const float* __restrict__ sb2, const float* __restrict__ sb3,
    const float* __restrict__ sb4,
    const float* __restrict__ mw, const float* __restrict__ mb,
    const float* __restrict__ mg, const float* __restrict__ mbt,
    const float* __restrict__ tw0, const float* __restrict__ tw1,
    const float* __restrict__ tw2,
    const float* __restrict__ tb0, const float* __restrict__ tb1,
    const float* __restrict__ tb2,
    const float* __restrict__ tg0, const float* __restrict__ tg1,
    const float* __restrict__ tg2,
    const float* __restrict__ tbt0, const float* __restrict__ tbt1,
    const float* __restrict__ tbt2,
    float* __restrict__ ws)
{
    const float* tws[3]  = {tw0, tw1, tw2};
    const float* tbs[3]  = {tb0, tb1, tb2};
    const float* tgs[3]  = {tg0, tg1, tg2};
    const float* tbts[3] = {tbt0, tbt1, tbt2};
    const int fsz[3] = {41, 51, 61};

    int gid = blockIdx.x * 256 + threadIdx.x;
    int gw = gid >> 6, lane = gid & 63;

    if (gw < 2048) {
        // A_eff[m][c] — wave-parallel over 1078 terms
        int m = gw >> 6, c = gw & 63;
        float acc = 0.f;
        for (int j = lane; j < 1078; j += 64) {
            float wv = mw[m * 1078 + j];
            float sv = 0.f;
            if (j < 183) {
                int r = j, fq = r / 61, h = r - fq * 61, k = c - h;
                if (k >= 0 && k < 4)  sv = sw0[fq * 4 + k];
            } else if (j < 411) {
                int r = j - 183, fq = r / 57, h = r - fq * 57, k = c - h;
                if (k >= 0 && k < 8)  sv = sw1[fq * 8 + k];
            } else if (j < 607) {
                int r = j - 411, fq = r / 49, h = r - fq * 49, k = c - h;
                if (k >= 0 && k < 16) sv = sw2[fq * 16 + k];
            } else if (j < 838) {
                int r = j - 607, fq = r / 33, h = r - fq * 33, k = c - h;
                if (k >= 0 && k < 32) sv = sw3[fq * 32 + k];
            } else {
                int r = j - 838;                 // nc1=1: h=0, k=c always valid
                sv = sw4[r * 64 + c];
            }
            acc += wv * sv;
        }
        for (int off = 32; off > 0; off >>= 1) acc += __shfl_down(acc, off);
        if (lane == 0) ws[A_OFF + m * 64 + c] = mg[m] * SBN * acc;
    } else if (gw < 2080) {
        // beta_eff[m]
        int m = gw - 2048;
        float acc = 0.f;
        for (int j = lane; j < 1078; j += 64) {
            float wv = mw[m * 1078 + j];
            float sv;
            if (j < 183)      sv = sb0[j / 61];
            else if (j < 411) sv = sb1[(j - 183) / 57];
            else if (j < 607) sv = sb2[(j - 411) / 49];
            else if (j < 838) sv = sb3[(j - 607) / 33];
            else              sv = sb4[j - 838];
            acc += wv * sv;
        }
        for (int off = 32; off > 0; off >>= 1) acc += __shfl_down(acc, off);
        if (lane == 0)
            ws[BETA_OFF + m] = mg[m] * SBN * (acc + mb[m]) + mbt[m];
    } else {
        int id2 = gid - 133120;                  // 2080 waves * 64
        if (id2 < 0) return;
        if (id2 < 192) {
            int fi = id2 >> 6, o = id2 & 63;
            ws[TBE_OFF + id2] = tgs[fi][o] * SBN * tbs[fi][o] + tbts[fi][o];
        } else if (id2 < 12480) {
            int idx = id2 - 192;
            int fi = idx >> 12, r = idx & 4095, o = r >> 6, k = r & 63;
            int sz = fsz[fi];
            float v = 0.f;
            if (k < sz) v = tgs[fi][o] * SBN * tws[fi][o * sz + k];
            ws[TWE_OFF + idx] = v;
        }
    }
}

// ---------------------------------------------------------------------------
// K2: Xs[b][m][t] (verified; FALLBACK PATH ONLY — main path fuses this
// computation into xt's prologue).
// ---------------------------------------------------------------------------
__global__ __launch_bounds__(256) void xs_kernel(const float* __restrict__ x,
                                                 float* __restrict__ ws)
{
    __shared__ float Ash[2048];
    __shared__ float Bsh[32];
    int tid = threadIdx.x;
    for (int i = tid; i < 2048; i += 256) Ash[i] = ws[A_OFF + i];
    if (tid < 32) Bsh[tid] = ws[BETA_OFF + tid];
    __syncthreads();

    int gid = blockIdx.x * 256 + tid;
    int b = gid / 1000, t = gid - b * 1000;
    const float* xp = x + b * 64000 + t;

    float acc[32];
#pragma unroll
    for (int m = 0; m < 32; ++m) acc[m] = Bsh[m];
#pragma unroll 4
    for (int c = 0; c < 64; ++c) {
        float xv = xp[c * 1000];
#pragma unroll
        for (int m = 0; m < 32; ++m) acc[m] += Ash[m * 64 + c] * xv;
    }
    float* op = ws + XS_OFF + b * 32000 + t;
#pragma unroll
    for (int m = 0; m < 32; ++m) op[m * 1000] = acc[m];
}

// ---------------------------------------------------------------------------
// conv8: rolling 8-output register window (kept for cov_kernel fallback)
// ---------------------------------------------------------------------------
__device__ __forceinline__ void conv8_vals(float* __restrict__ a,
                                           const float* __restrict__ xp,
                                           const unsigned short* __restrict__ wp,
                                           int szp, float bias)
{
    float xw[8];
#pragma unroll
    for (int i = 0; i < 8; ++i) { a[i] = bias; xw[i] = xp[i]; }
    for (int k = 0; k < szp; k += 8) {
#pragma unroll
        for (int p = 0; p < 8; ++p) {
            float w = bf2f(wp[(k + p) * 64]);
#pragma unroll
            for (int i = 0; i < 8; ++i) a[i] += w * xw[(p + i) & 7];
            xw[p] = xp[k + p + 8];
        }
    }
}

// ---------------------------------------------------------------------------
// conv16 v4 (verified r8): weights read from LDS as packed bf16 pairs
// in-loop; no persistent weight registers (register array spilled in r7).
// Tap order k+p ascending -> bit-identical outputs.
// ---------------------------------------------------------------------------
template<int SZP>
__device__ __forceinline__ void conv16(float* __restrict__ a,
                                       const float* __restrict__ xp,
                                       const unsigned int* __restrict__ w2o,
                                       float bias)
{
    float xw[16];
#pragma unroll
    for (int i = 0; i < 16; ++i) { a[i] = bias; xw[i] = xp[i]; }
#pragma unroll
    for (int k = 0; k < SZP; k += 8) {
#pragma unroll
        for (int p = 0; p < 8; ++p) {
            unsigned int u = w2o[((k + p) >> 1) * 64];   // LDS, offset imm
            float w = ((p & 1) == 0) ? __uint_as_float(u << 16)
                                     : __uint_as_float(u & 0xffff0000u);
#pragma unroll
            for (int i = 0; i < 16; ++i)
                a[i] += w * xw[(k + p + i) & 15];
            xw[(k + p) & 15] = xp[k + p + 16];
        }
    }
}

// per-(bank,thalf) task: one channel per lane, 64 consecutive t = one full
// 128B line per thread (fixed the 1.6x partial-line write amplification;
// r8: WRITE_SIZE 49.2MB = ideal).
template<int SZP, int BASE>
__device__ __forceinline__ void xt_task(const float* __restrict__ xp0,
                                        const unsigned int* __restrict__ w2o,
                                        float bias,
                                        unsigned short* __restrict__ op,
                                        int tbase)
{
#pragma unroll 1
    for (int s = 0; s < 4; ++s) {
        float a[16];
        conv16<SZP>(a, xp0 + s * 16 + BASE, w2o, bias);
#pragma unroll
        for (int half = 0; half < 2; ++half) {
            short8 hv;
#pragma unroll
            for (int i = 0; i < 8; ++i) {
                int gt = tbase + s * 16 + half * 8 + i;
                hv[i] = (short)((gt < 1000) ? f2bf(a[half * 8 + i]) : 0);
            }
            *(short8*)&op[s * 16 + half * 8] = hv;
        }
    }
}

// ---------------------------------------------------------------------------
// K3a v8 (this round): fused-xs prologue split over ALL 384 threads.
// r16 post-mortem: fused prologue cost ~33us (xt 90->123) because only
// 200/384 threads were active (3.1 waves/block) during the serial
// barrier-to-barrier phase.  v8: 400 tasks = 200 q x 2 m-halves; each
// thread computes 16 m's for its (q,mh).  Per-element order unchanged
// (init Bsh[m], c ascending) -> bit-identical.  x loads per q shared by
// the thread pair (same addresses -> L1 broadcast).  Active waves 3.1->6.
// Watch: VGPR <=128, WRITE 49.2MB (spill alert -> revert).
// ---------------------------------------------------------------------------
__global__ __launch_bounds__(384) void xt_kernel(const float* __restrict__ x,
                                                 float* __restrict__ ws)
{
    __shared__ float xs_sh[32 * 201];          // stride 201 (9 mod 32), conflict-free
    __shared__ unsigned int tw2_sh[5376];      // packed pairs [bank][kt2][64]
    __shared__ float tb_sh[192];
    __shared__ float Ash[2048];                // A_eff[m][c] for fused xs
    __shared__ float Bsh[32];                  // beta_eff

    int tid = threadIdx.x;
    int wg = blockIdx.x;
    int b = wg >> 3, chunk = wg & 7;
    int t0 = chunk * 128;

    // stage A_eff/beta + packed weights + biases (all independent)
    for (int i = tid; i < 2048; i += 384) Ash[i] = ws[A_OFF + i];
    if (tid < 32) Bsh[tid] = ws[BETA_OFF + tid];
    for (int idx = tid; idx < 5376; idx += 384) {
        int bank, rem;
        if (idx < 1536)      { bank = 0; rem = idx; }
        else if (idx < 3328) { bank = 1; rem = idx - 1536; }
        else                 { bank = 2; rem = idx - 3328; }
        int kt2 = rem >> 6, o = rem & 63;
        unsigned int lo = f2bf(ws[TWE_OFF + bank * 4096 + o * 64 + 2 * kt2]);
        unsigned int hi = f2bf(ws[TWE_OFF + bank * 4096 + o * 64 + 2 * kt2 + 1]);
        tw2_sh[idx] = lo | (hi << 16);
    }
    if (tid < 192) tb_sh[tid] = ws[TBE_OFF + tid];
    __syncthreads();                           // Ash/Bsh ready

    // fused xs: 400 tasks = 200 q x 2 m-halves, over all 384 threads
    for (int task = tid; task < 400; task += 384) {
        int q = task >> 1, mh = (task & 1) * 16;
        int gt = t0 - 30 + q;
        float acc[16];
        if (gt >= 0 && gt < 1000) {
            const float* xp = x + b * 64000 + gt;
#pragma unroll
            for (int mm = 0; mm < 16; ++mm) acc[mm] = Bsh[mh + mm];
#pragma unroll 4
            for (int c = 0; c < 64; ++c) {
                float xv = xp[c * 1000];
#pragma unroll
                for (int mm = 0; mm < 16; ++mm)
                    acc[mm] += Ash[(mh + mm) * 64 + c] * xv;
            }
        } else {
#pragma unroll
            for (int mm = 0; mm < 16; ++mm) acc[mm] = 0.f;
        }
#pragma unroll
        for (int mm = 0; mm < 16; ++mm) xs_sh[(mh + mm) * 201 + q] = acc[mm];
    }
    __syncthreads();

    unsigned short* xtg = (unsigned short*)(ws + XT_OFF);
    const int lane = tid & 63;
    const int wv   = tid >> 6;          // 0..5
    const int bank = wv % 3, thalf = wv / 3;
    const int o = lane, m = o >> 1;
    const int ch = bank * 64 + o;
    float bias = tb_sh[ch];
    int tbase = t0 + thalf * 64;
    unsigned short* op = &xtg[(size_t)(b * 192 + ch) * 1024 + tbase];
    const float* xp0 = &xs_sh[m * 201 + thalf * 64];

    if (bank == 0)      xt_task<48, 10>(xp0, &tw2_sh[0]    + o, bias, op, tbase);
    else if (bank == 1) xt_task<56, 5>( xp0, &tw2_sh[1536] + o, bias, op, tbase);
    else                xt_task<64, 0>( xp0, &tw2_sh[3328] + o, bias, op, tbase);
}

// ---------------------------------------------------------------------------
// K3b v2 (verified r12): Gram MFMA, 512 threads (8 waves), grid 256.
// ---------------------------------------------------------------------------
__global__ __launch_bounds__(512) void gram_kernel(float* __restrict__ ws)
{
    __shared__ __align__(16) unsigned short xsh[192 * 136];   // 52,224 B

    int tid = threadIdx.x;
    int b = blockIdx.x >> 1, h = blockIdx.x & 1;
    int nrows = h ? 192 : 128;

    const unsigned short* xtg = (const unsigned short*)(ws + XT_OFF);
    const unsigned short* gb = xtg + (size_t)b * 192 * 1024;

    floatx4 acc[3][2];
#pragma unroll
    for (int t = 0; t < 3; ++t)
#pragma unroll
        for (int sjl = 0; sjl < 2; ++sjl) acc[t][sjl] = (floatx4){0.f, 0.f, 0.f, 0.f};

    const int lane = tid & 63;
    const int wv8  = tid >> 6;          // 0..7
    const int wvr  = wv8 & 3;           // row quadrant
    const int sjb  = (wv8 >> 2) * 2;    // sj base: 0 or 2
    const int m15  = lane & 15;
    const int quad = lane >> 4;
    int nloads = nrows * 16;

    for (int t0 = 0; t0 < 1024; t0 += 128) {
        for (int idx = tid; idx < nloads; idx += 512) {
            int row = idx >> 4, c8 = idx & 15;
            *(short8*)&xsh[row * 136 + c8 * 8] =
                *(const short8*)&gb[(size_t)row * 1024 + t0 + c8 * 8];
        }
        __syncthreads();
        if (h == 0) {
#pragma unroll
            for (int k0 = 0; k0 < 128; k0 += 32) {
                short8 a0 = *(const short8*)&xsh[(      wvr * 16 + m15) * 136 + quad * 8 + k0];
                short8 a1 = *(const short8*)&xsh[( 64 + wvr * 16 + m15) * 136 + quad * 8 + k0];
#pragma unroll
                for (int sjl = 0; sjl < 2; ++sjl) {
                    int sj = sjb + sjl;
                    short8 b0 = *(const short8*)&xsh[(      sj * 16 + m15) * 136 + quad * 8 + k0];
                    short8 b1 = *(const short8*)&xsh[( 64 + sj * 16 + m15) * 136 + quad * 8 + k0];
                    acc[0][sjl] = __builtin_amdgcn_mfma_f32_16x16x32_bf16(a0, b0, acc[0][sjl], 0, 0, 0);
                    acc[1][sjl] = __builtin_amdgcn_mfma_f32_16x16x32_bf16(a1, b0, acc[1][sjl], 0, 0, 0);
                    acc[2][sjl] = __builtin_amdgcn_mfma_f32_16x16x32_bf16(a1, b1, acc[2][sjl], 0, 0, 0);
                }
            }
        } else {
#pragma unroll
            for (int k0 = 0; k0 < 128; k0 += 32) {
                short8 a2 = *(const short8*)&xsh[(128 + wvr * 16 + m15) * 136 + quad * 8 + k0];
#pragma unroll
                for (int sjl = 0; sjl < 2; ++sjl) {
                    int sj = sjb + sjl;
                    short8 b0 = *(const short8*)&xsh[(      sj * 16 + m15) * 136 + quad * 8 + k0];
                    short8 b1 = *(const short8*)&xsh[( 64 + sj * 16 + m15) * 136 + quad * 8 + k0];
                    short8 b2 = *(const short8*)&xsh[(128 + sj * 16 + m15) * 136 + quad * 8 + k0];
                    acc[0][sjl] = __builtin_amdgcn_mfma_f32_16x16x32_bf16(a2, b0, acc[0][sjl], 0, 0, 0);
                    acc[1][sjl] = __builtin_amdgcn_mfma_f32_16x16x32_bf16(a2, b1, acc[1][sjl], 0, 0, 0);
                    acc[2][sjl] = __builtin_amdgcn_mfma_f32_16x16x32_bf16(a2, b2, acc[2][sjl], 0, 0, 0);
                }
            }
        }
        __syncthreads();
    }

    const float sc = 1.0f / 999.0f;
#pragma unroll
    for (int t = 0; t < 3; ++t) {
        int tileid = h ? (3 + t) : t;
        float* xbp = ws + XBP_OFF + b * 24576 + tileid * 4096;
#pragma unroll
        for (int sjl = 0; sjl < 2; ++sjl)
#pragma unroll
            for (int r = 0; r < 4; ++r) {
                int i = wvr * 16 + quad * 4 + r;    // C/D: row = quad*4 + reg
                int j = (sjb + sjl) * 16 + m15;     //      col = lane & 15
                xbp[i * 64 + j] = acc[t][sjl][r] * sc;
            }
    }
}

// ---------------------------------------------------------------------------
// K3 (fallback, small ws): r8's fused conv+Gram kernel (verified).
// ---------------------------------------------------------------------------
__global__ __launch_bounds__(256, 3) void cov_kernel(float* __restrict__ ws)
{
    __shared__ float xs_sh[32 * 129];
    __shared__ __align__(16) unsigned short xt_sh[2 * 64 * 72];
    __shared__ unsigned short tw_sh[120 * 64];
    __shared__ float tb_sh[128];

    int tid = threadIdx.x;
    int wg = blockIdx.x;
    int b = wg / 6, tile = wg - b * 6;
    const int TIa[6] = {0, 1, 1, 2, 2, 2};
    const int TJa[6] = {0, 0, 1, 0, 1, 2};
    int I = TIa[tile], J = TJa[tile];
    const int fpad[3] = {20, 25, 30};
    const int fszp[3] = {48, 56, 64};
    int padI = fpad[I], szpI = fszp[I];
    int padJ = fpad[J], szpJ = fszp[J];
    bool diag = (I == J);

    int nI = szpI * 64;
    for (int idx = tid; idx < nI; idx += 256) {
        int kt = idx >> 6, o = idx & 63;
        tw_sh[idx] = f2bf(ws[TWE_OFF + I * 4096 + o * 64 + kt]);
    }
    if (!diag) {
        int nJ = szpJ * 64;
        for (int idx = tid; idx < nJ; idx += 256) {
            int kt = idx >> 6, o = idx & 63;
            tw_sh[nI + idx] = f2bf(ws[TWE_OFF + J * 4096 + o * 64 + kt]);
        }
    }
    if (tid < 64)        tb_sh[tid] = ws[TBE_OFF + I * 64 + tid];
    else if (tid < 128)  tb_sh[tid] = ws[TBE_OFF + J * 64 + (tid - 64)];

    floatx4 acc[4];
#pragma unroll
    for (int sj = 0; sj < 4; ++sj) acc[sj] = (floatx4){0.f, 0.f, 0.f, 0.f};

    const float* xsrow = ws + XS_OFF + b * 32000;
    unsigned short* xtI = xt_sh;
    unsigned short* xtJ = diag ? xt_sh : (xt_sh + 64 * 72);

    const int lane = tid & 63;
    const int wv   = tid >> 6;
    const int m15  = lane & 15;
    const int quad = lane >> 4;

    for (int t0 = 0; t0 < 1000; t0 += 64) {
        for (int idx = tid; idx < 4096; idx += 256) {
            int m = idx >> 7, q = idx & 127;
            int gt = t0 - 30 + q;
            xs_sh[m * 129 + q] = (gt >= 0 && gt < 1000) ? xsrow[m * 1000 + gt] : 0.f;
        }
        __syncthreads();
        for (int it = 0; it < 2; ++it) {
            int o   = lane;
            int grp = wv + it * 4;
            int tlb = grp * 8;
            int m   = o >> 1;
            float a[8];
            conv8_vals(a, &xs_sh[m * 129 + tlb + (30 - padI)], &tw_sh[o],
                       szpI, tb_sh[o]);
            short8 hv;
#pragma unroll
            for (int i = 0; i < 8; ++i) {
                int gt = t0 + tlb + i;
                hv[i] = (short)((gt < 1000) ? f2bf(a[i]) : 0);
            }
            *(short8*)&xtI[o * 72 + tlb] = hv;
            if (!diag) {
                conv8_vals(a, &xs_sh[m * 129 + tlb + (30 - padJ)], &tw_sh[nI + o],
                           szpJ, tb_sh[64 + o]);
#pragma unroll
                for (int i = 0; i < 8; ++i) {
                    int gt = t0 + tlb + i;
                    hv[i] = (short)((gt < 1000) ? f2bf(a[i]) : 0);
                }
                *(short8*)&xtJ[o * 72 + tlb] = hv;
            }
        }
        __syncthreads();
        const unsigned short* ap = &xtI[(wv * 16 + m15) * 72 + quad * 8];
#pragma unroll
        for (int k0 = 0; k0 < 64; k0 += 32) {
            short8 af = *(const short8*)(ap + k0);
#pragma unroll
            for (int sj = 0; sj < 4; ++sj) {
                short8 bf = *(const short8*)&xtJ[(sj * 16 + m15) * 72 + quad * 8 + k0];
                acc[sj] = __builtin_amdgcn_mfma_f32_16x16x32_bf16(af, bf, acc[sj],
                                                                  0, 0, 0);
            }
        }
        __syncthreads();
    }

    float* xbp = ws + XBP_OFF + b * 24576 + tile * 4096;
    const float sc = 1.0f / 999.0f;
#pragma unroll
    for (int sj = 0; sj < 4; ++sj)
#pragma unroll
        for (int r = 0; r < 4; ++r) {
            int i = wv * 16 + quad * 4 + r;
            int j = sj * 16 + m15;
            xbp[i * 64 + j] = acc[sj][r] * sc;
        }
}

// ---------------------------------------------------------------------------
// K4 v6 (verified r8, session-best; FINAL): 512 threads, trailing update
// sized to hipcc's VGPR cap (= 65536/block_size; launch-bounds 2nd arg and
// waves_per_eu both ineffective/harmful).  8x4 tiles, k-chunk 4 (~100 VGPR
// <= 128 cap, spill-free).  Ladder: 256->121us, 512->91us, 1024->127us.
// ---------------------------------------------------------------------------
#define LSTR 196
__device__ __forceinline__ int lidx(int i, int c) {
    return i * LSTR + ((((c >> 2) ^ ((i >> 3) & 7)) << 2) | (c & 3));
}

// 16x16 diag Cholesky in registers, lanes 0-15 of wave 0 (call under tid<16)
__device__ __forceinline__ void diag16(float* Lm, int j0, int i,
                                       float* invd_sh)
{
    float r[16];
#pragma unroll
    for (int c = 0; c < 16; ++c) r[c] = Lm[lidx(j0 + i, j0 + c)];
#pragma unroll
    for (int jj = 0; jj < 16; ++jj) {
        float d = __shfl(r[jj], jj);
        d = fmaxf(d, 1e-20f);
        float s = sqrtf(d);
        float inv = 1.0f / s;
        if (i == jj) { r[jj] = s; invd_sh[jj] = inv; }
        else if (i > jj) r[jj] *= inv;
#pragma unroll
        for (int cc = jj + 1; cc < 16; ++cc) {
            float vc = __shfl(r[jj], cc);
            if (i >= cc) r[cc] -= r[jj] * vc;
        }
    }
#pragma unroll
    for (int c = 0; c < 16; ++c)
        if (c <= i) Lm[lidx(j0 + i, j0 + c)] = r[c];
}

__global__ __launch_bounds__(512) void chol_kernel(const float* __restrict__ ws,
                                                   const float* __restrict__ fcw,
                                                   const float* __restrict__ fcb,
                                                   float* __restrict__ out)
{
    __shared__ __align__(16) float L[192 * LSTR];   // 150,528 B
    __shared__ float invd_sh[16];
    __shared__ float red[8][4];

    int b = blockIdx.x, tid = threadIdx.x;
    const float* Xb = ws + XBP_OFF + b * 24576;
    const int TIa[6] = {0, 1, 1, 2, 2, 2};
    const int TJa[6] = {0, 0, 1, 0, 1, 2};

    // load packed Gram tiles -> swizzled LDS (float4; c always mult of 4)
    for (int idx = tid; idx < 6144; idx += 512) {
        int fi = idx << 2;
        int t = fi >> 12, r = (fi >> 6) & 63, c = fi & 63;
        floatx4 val = *(const floatx4*)&Xb[fi];
        *(floatx4*)&L[lidx(TIa[t] * 64 + r, TJa[t] * 64 + c)] = val;
    }
    __syncthreads();

    // prologue: factor panel 0 diag
    if (tid < 16) diag16(L, 0, tid, invd_sh);
    __syncthreads();

    for (int p = 0; p <= 10; ++p) {
        int j0 = p * 16, j1 = j0 + 16;

        // --- B: TRSM, one row per thread, vectorized row access ---
        {
            int i = j1 + tid;
            if (i < 192) {
                floatx4 vv[4];
#pragma unroll
                for (int q = 0; q < 4; ++q)
                    vv[q] = *(floatx4*)&L[lidx(i, j0 + 4 * q)];
                float v[16];
#pragma unroll
                for (int k = 0; k < 16; ++k) v[k] = vv[k >> 2][k & 3];
#pragma unroll
                for (int k = 0; k < 16; ++k) {
                    float vk = v[k];
#pragma unroll
                    for (int p2 = 0; p2 < k; ++p2)
                        vk -= v[p2] * L[lidx(j0 + k, j0 + p2)];
                    v[k] = vk * invd_sh[k];
                }
#pragma unroll
                for (int k = 0; k < 16; ++k) vv[k >> 2][k & 3] = v[k];
#pragma unroll
                for (int q = 0; q < 4; ++q)
                    *(floatx4*)&L[lidx(i, j0 + 4 * q)] = vv[q];
            }
        }
        __syncthreads();

        // --- C: trailing rank-16 update + hidden diag factorization ---
        int RT = (192 - j1) >> 3;          // 8-row blocks
        int nt = RT * RT + RT;             // 8x4 lower-tri tiles: ti^2+ti+tj
        if (tid < 64) {
            // wave 0: update next diag 16x16 block (tiles t=0..5), then
            // factor it in-wave while waves 1-7 grind the remaining tiles.
            int r = tid & 15, cq = tid >> 4;
            floatx4 a4 = *(floatx4*)&L[lidx(j1 + r, j1 + cq * 4)];
#pragma unroll
            for (int k = 0; k < 16; ++k) {
                float pr = L[lidx(j1 + r, j0 + k)];
#pragma unroll
                for (int cc = 0; cc < 4; ++cc)
                    a4[cc] -= pr * L[lidx(j1 + cq * 4 + cc, j0 + k)];
            }
            *(floatx4*)&L[lidx(j1 + r, j1 + cq * 4)] = a4;
            if (tid < 16) diag16(L, j1, tid, invd_sh);
        } else {
            for (int t = 6 + (tid - 64); t < nt; t += 448) {
                int ti = (int)(sqrtf((float)t + 0.25f) - 0.5f);
                while (ti * ti + ti > t) --ti;
                while ((ti + 1) * (ti + 1) + (ti + 1) <= t) ++ti;
                int tj = t - ti * ti - ti;        // tj in [0, 2ti+2)
                int i0 = j1 + 8 * ti, c0 = j1 + 4 * tj;
                floatx4 a[8];
#pragma unroll
                for (int r = 0; r < 8; ++r)
                    a[r] = *(floatx4*)&L[lidx(i0 + r, c0)];
#pragma unroll 1
                for (int kk = 0; kk < 16; kk += 4) {
                    floatx4 pi[8], pc[4];
#pragma unroll
                    for (int r = 0; r < 8; ++r)
                        pi[r] = *(floatx4*)&L[lidx(i0 + r, j0 + kk)];
#pragma unroll
                    for (int c = 0; c < 4; ++c)
                        pc[c] = *(floatx4*)&L[lidx(c0 + c, j0 + kk)];
#pragma unroll
                    for (int k = 0; k < 4; ++k)
#pragma unroll
                        for (int r = 0; r < 8; ++r) {
                            float ar = pi[r][k];
#pragma unroll
                            for (int c = 0; c < 4; ++c)
                                a[r][c] -= ar * pc[c][k];
                        }
                }
#pragma unroll
                for (int r = 0; r < 8; ++r)
                    *(floatx4*)&L[lidx(i0 + r, c0)] = a[r];
            }
        }
        __syncthreads();
    }

    // fused tangent + FC (incremental tril index)
    float a0 = 0.f, a1 = 0.f, a2 = 0.f, a3 = 0.f;
    for (int d = tid; d < 192; d += 512) {
        float v = logf(fmaxf(L[lidx(d, d)], 1e-30f));
        a0 += v * fcw[d];
        a1 += v * fcw[18528 + d];
        a2 += v * fcw[2 * 18528 + d];
        a3 += v * fcw[3 * 18528 + d];
    }
    {
        int e = tid;
        float fe = (float)e;
        int r = (int)((1.0f + sqrtf(1.0f + 8.0f * fe)) * 0.5f);
        if (r < 1) r = 1;
        while (r * (r - 1) / 2 > e) --r;
        while ((r + 1) * r / 2 <= e) ++r;
        int c = e - r * (r - 1) / 2;
        for (; e < 18336; e += 512) {
            float v = L[lidx(r, c)];
            int dd = 192 + e;
            a0 += v * fcw[dd];
            a1 += v * fcw[18528 + dd];
            a2 += v * fcw[2 * 18528 + dd];
            a3 += v * fcw[3 * 18528 + dd];
            c += 512;
            while (c >= r) { c -= r; ++r; }
        }
    }
    for (int off = 32; off > 0; off >>= 1) {
        a0 += __shfl_down(a0, off);
        a1 += __shfl_down(a1, off);
        a2 += __shfl_down(a2, off);
        a3 += __shfl_down(a3, off);
    }
    int wv = tid >> 6, ln = tid & 63;
    if (ln == 0) { red[wv][0] = a0; red[wv][1] = a1; red[wv][2] = a2; red[wv][3] = a3; }
    __syncthreads();
    if (tid < 4) {
        float s = red[0][tid] + red[1][tid] + red[2][tid] + red[3][tid]
                + red[4][tid] + red[5][tid] + red[6][tid] + red[7][tid]
                + fcb[tid];
        out[b * 4 + tid] = s;
    }
}

// ---------------------------------------------------------------------------
extern "C" void kernel_launch(void* const* d_in, const int* in_sizes, int n_in,
                              void* d_out, int out_size, void* d_ws, size_t ws_size,
                              hipStream_t stream)
{
    float* ws = (float*)d_ws;

    prep_kernel<<<569, 256, 0, stream>>>(
        (const float*)d_in[1], (const float*)d_in[3], (const float*)d_in[5],
        (const float*)d_in[7], (const float*)d_in[9],
        (const float*)d_in[2], (const float*)d_in[4], (const float*)d_in[6],
        (const float*)d_in[8], (const float*)d_in[10],
        (const float*)d_in[11], (const float*)d_in[12], (const float*)d_in[13],
        (const float*)d_in[14],
        (const float*)d_in[15], (const float*)d_in[19], (const float*)d_in[23],
        (const float*)d_in[16], (const float*)d_in[20], (const float*)d_in[24],
        (const float*)d_in[17], (const float*)d_in[21], (const float*)d_in[25],
        (const float*)d_in[18], (const float*)d_in[22], (const float*)d_in[26], ws);
    if (ws_size >= WS_NEED) {
        // main path: xs fused into xt — no separate xs launch
        xt_kernel<<<1024, 384, 0, stream>>>((const float*)d_in[0], ws);
        gram_kernel<<<256, 512, 0, stream>>>(ws);     // v2: 8 waves/block
    } else {
        xs_kernel<<<500, 256, 0, stream>>>((const float*)d_in[0], ws);
        cov_kernel<<<768, 256, 0, stream>>>(ws);      // r8 fused fallback
    }
    chol_kernel<<<128, 512, 0, stream>>>(ws, (const float*)d_in[27],
                                         (const float*)d_in[28], (float*)d_out);
}

// Round 18
// 339.504 us; speedup vs baseline: 1.0378x; 1.0378x over previous
//
#include <hip/hip_runtime.h>
#include <hip/hip_bf16.h>
#include <math.h>

// ---- problem constants ----
// B=128, NC=64, T=1000, SPATIAL_MERGE=32, FILTERS={41,51,61}, NF=192
// FEATURE_DIM = {(3,4),(4,8),(4,16),(7,32),(240,64)}, SUM_SP=1078
// FC_IN = 18528, N_CLASS=4.  Input/output dtype: float32 (confirmed r6/r7).

// workspace layout (float offsets)
#define A_OFF    0         // 32*64
#define BETA_OFF 2048      // 32
#define TBE_OFF  2080      // 192
#define TWE_OFF  2304      // 3*4096, taps zero-padded to 64
#define XS_OFF   14592     // 128*32*1000 (fallback path only)
#define XBP_OFF  4110592   // 128 * 6 tiles * 64*64 packed (end 7,256,320 floats)
#define XT_OFF   7256320   // bf16 Xt [b][192][1024] = 12,582,912 floats worth
#define WS_NEED  ((size_t)19839232 * 4)   // 79.4 MB -> split path; else fused

#define SBN 0.9999950000374997f   // 1/sqrt(1+1e-5)

typedef short short8 __attribute__((ext_vector_type(8)));    // 8 bf16 (4 VGPRs)
typedef float floatx4 __attribute__((ext_vector_type(4)));   // MFMA accumulator

__device__ __forceinline__ unsigned short f2bf(float f) {    // fp32 -> bf16 (RNE)
    unsigned u = __float_as_uint(f);
    u += 0x7FFFu + ((u >> 16) & 1u);
    return (unsigned short)(u >> 16);
}
__device__ __forceinline__ float bf2f(unsigned short h) {
    return __uint_as_float(((unsigned)h) << 16);
}

// ---------------------------------------------------------------------------
// K1: wave-parallel folding (verified r10).
// ---------------------------------------------------------------------------
__global__ __launch_bounds__(256) void prep_kernel(
    const float* __restrict__ sw0, const float* __restrict__ sw1,
    const float* __restrict__ sw2, const float* __restrict__ sw3,
    const float* __restrict__ sw4,
    const float* __restrict__ sb0, const float* __restrict__ sb1,
    const float* __restrict__ sb2, const float* __restrict__ sb3,
    const float* __restrict__ sb4,
    const float* __restrict__ mw, const float* __restrict__ mb,
    const float* __restrict__ mg, const float* __restrict__ mbt,
    const float* __restrict__ tw0, const float* __restrict__ tw1,
    const float* __restrict__ tw2,
    const float* __restrict__ tb0, const float* __restrict__ tb1,
    const float* __restrict__ tb2,
    const float* __restrict__ tg0, const float* __restrict__ tg1,
    const float* __restrict__ tg2,
    const float* __restrict__ tbt0, const float* __restrict__ tbt1,
    const float* __restrict__ tbt2,
    float* __restrict__ ws)
{
    const float* tws[3]  = {tw0, tw1, tw2};
    const float* tbs[3]  = {tb0, tb1, tb2};
    const float* tgs[3]  = {tg0, tg1, tg2};
    const float* tbts[3] = {tbt0, tbt1, tbt2};
    const int fsz[3] = {41, 51, 61};

    int gid = blockIdx.x * 256 + threadIdx.x;
    int gw = gid >> 6, lane = gid & 63;

    if (gw < 2048) {
        // A_eff[m][c] — wave-parallel over 1078 terms
        int m = gw >> 6, c = gw & 63;
        float acc = 0.f;
        for (int j = lane; j < 1078; j += 64) {
            float wv = mw[m * 1078 + j];
            float sv = 0.f;
            if (j < 183) {
                int r = j, fq = r / 61, h = r - fq * 61, k = c - h;
                if (k >= 0 && k < 4)  sv = sw0[fq * 4 + k];
            } else if (j < 411) {
                int r = j - 183, fq = r / 57, h = r - fq * 57, k = c - h;
                if (k >= 0 && k < 8)  sv = sw1[fq * 8 + k];
            } else if (j < 607) {
                int r = j - 411, fq = r / 49, h = r - fq * 49, k = c - h;
                if (k >= 0 && k < 16) sv = sw2[fq * 16 + k];
            } else if (j < 838) {
                int r = j - 607, fq = r / 33, h = r - fq * 33, k = c - h;
                if (k >= 0 && k < 32) sv = sw3[fq * 32 + k];
            } else {
                int r = j - 838;                 // nc1=1: h=0, k=c always valid
                sv = sw4[r * 64 + c];
            }
            acc += wv * sv;
        }
        for (int off = 32; off > 0; off >>= 1) acc += __shfl_down(acc, off);
        if (lane == 0) ws[A_OFF + m * 64 + c] = mg[m] * SBN * acc;
    } else if (gw < 2080) {
        // beta_eff[m]
        int m = gw - 2048;
        float acc = 0.f;
        for (int j = lane; j < 1078; j += 64) {
            float wv = mw[m * 1078 + j];
            float sv;
            if (j < 183)      sv = sb0[j / 61];
            else if (j < 411) sv = sb1[(j - 183) / 57];
            else if (j < 607) sv = sb2[(j - 411) / 49];
            else if (j < 838) sv = sb3[(j - 607) / 33];
            else              sv = sb4[j - 838];
            acc += wv * sv;
        }
        for (int off = 32; off > 0; off >>= 1) acc += __shfl_down(acc, off);
        if (lane == 0)
            ws[BETA_OFF + m] = mg[m] * SBN * (acc + mb[m]) + mbt[m];
    } else {
        int id2 = gid - 133120;                  // 2080 waves * 64
        if (id2 < 0) return;
        if (id2 < 192) {
            int fi = id2 >> 6, o = id2 & 63;
            ws[TBE_OFF + id2] = tgs[fi][o] * SBN * tbs[fi][o] + tbts[fi][o];
        } else if (id2 < 12480) {
            int idx = id2 - 192;
            int fi = idx >> 12, r = idx & 4095, o = r >> 6, k = r & 63;
            int sz = fsz[fi];
            float v = 0.f;
            if (k < sz) v = tgs[fi][o] * SBN * tws[fi][o * sz + k];
            ws[TWE_OFF + idx] = v;
        }
    }
}

// ---------------------------------------------------------------------------
// K2: Xs[b][m][t] (verified; FALLBACK PATH ONLY — main path fuses this
// computation into xt's prologue).
// ---------------------------------------------------------------------------
__global__ __launch_bounds__(256) void xs_kernel(const float* __restrict__ x,
                                                 float* __restrict__ ws)
{
    __shared__ float Ash[2048];
    __shared__ float Bsh[32];
    int tid = threadIdx.x;
    for (int i = tid; i < 2048; i += 256) Ash[i] = ws[A_OFF + i];
    if (tid < 32) Bsh[tid] = ws[BETA_OFF + tid];
    __syncthreads();

    int gid = blockIdx.x * 256 + tid;
    int b = gid / 1000, t = gid - b * 1000;
    const float* xp = x + b * 64000 + t;

    float acc[32];
#pragma unroll
    for (int m = 0; m < 32; ++m) acc[m] = Bsh[m];
#pragma unroll 4
    for (int c = 0; c < 64; ++c) {
        float xv = xp[c * 1000];
#pragma unroll
        for (int m = 0; m < 32; ++m) acc[m] += Ash[m * 64 + c] * xv;
    }
    float* op = ws + XS_OFF + b * 32000 + t;
#pragma unroll
    for (int m = 0; m < 32; ++m) op[m * 1000] = acc[m];
}

// ---------------------------------------------------------------------------
// conv8: rolling 8-output register window (kept for cov_kernel fallback)
// ---------------------------------------------------------------------------
__device__ __forceinline__ void conv8_vals(float* __restrict__ a,
                                           const float* __restrict__ xp,
                                           const unsigned short* __restrict__ wp,
                                           int szp, float bias)
{
    float xw[8];
#pragma unroll
    for (int i = 0; i < 8; ++i) { a[i] = bias; xw[i] = xp[i]; }
    for (int k = 0; k < szp; k += 8) {
#pragma unroll
        for (int p = 0; p < 8; ++p) {
            float w = bf2f(wp[(k + p) * 64]);
#pragma unroll
            for (int i = 0; i < 8; ++i) a[i] += w * xw[(p + i) & 7];
            xw[p] = xp[k + p + 8];
        }
    }
}

// ---------------------------------------------------------------------------
// conv16 v4 (verified r8): weights read from LDS as packed bf16 pairs
// in-loop; no persistent weight registers (register array spilled in r7).
// Tap order k+p ascending -> bit-identical outputs.
// ---------------------------------------------------------------------------
template<int SZP>
__device__ __forceinline__ void conv16(float* __restrict__ a,
                                       const float* __restrict__ xp,
                                       const unsigned int* __restrict__ w2o,
                                       float bias)
{
    float xw[16];
#pragma unroll
    for (int i = 0; i < 16; ++i) { a[i] = bias; xw[i] = xp[i]; }
#pragma unroll
    for (int k = 0; k < SZP; k += 8) {
#pragma unroll
        for (int p = 0; p < 8; ++p) {
            unsigned int u = w2o[((k + p) >> 1) * 64];   // LDS, offset imm
            float w = ((p & 1) == 0) ? __uint_as_float(u << 16)
                                     : __uint_as_float(u & 0xffff0000u);
#pragma unroll
            for (int i = 0; i < 16; ++i)
                a[i] += w * xw[(k + p + i) & 15];
            xw[(k + p) & 15] = xp[k + p + 16];
        }
    }
}

// per-(bank,thalf) task: one channel per lane, 64 consecutive t = one full
// 128B line per thread (fixed the 1.6x partial-line write amplification;
// r8: WRITE_SIZE 49.2MB = ideal).
template<int SZP, int BASE>
__device__ __forceinline__ void xt_task(const float* __restrict__ xp0,
                                        const unsigned int* __restrict__ w2o,
                                        float bias,
                                        unsigned short* __restrict__ op,
                                        int tbase)
{
#pragma unroll 1
    for (int s = 0; s < 4; ++s) {
        float a[16];
        conv16<SZP>(a, xp0 + s * 16 + BASE, w2o, bias);
#pragma unroll
        for (int half = 0; half < 2; ++half) {
            short8 hv;
#pragma unroll
            for (int i = 0; i < 8; ++i) {
                int gt = tbase + s * 16 + half * 8 + i;
                hv[i] = (short)((gt < 1000) ? f2bf(a[half * 8 + i]) : 0);
            }
            *(short8*)&op[s * 16 + half * 8] = hv;
        }
    }
}

// ---------------------------------------------------------------------------
// K3a v7 (verified r16 = session-best, FINAL; v8 pair-split reverted):
// fused xs prologue on 200 threads, each computing all 32 m's per q.
// All lanes read the SAME Ash[m*64+c] per step -> pure LDS broadcast,
// 0 bank conflicts (r16 counter).  v8's (q,m-half) pairing put the two
// halves 1024 floats apart = same bank -> 6.46M 2-way conflicts (+10us)
// AND doubled global-load issue (both pair threads load the same 64 xv)
// -> net regression 123->135us.  v7 is this kernel's optimum.
// LDS 56.3KB (2 blocks/CU); VGPR 128; WRITE/FETCH ideal.
// ---------------------------------------------------------------------------
__global__ __launch_bounds__(384) void xt_kernel(const float* __restrict__ x,
                                                 float* __restrict__ ws)
{
    __shared__ float xs_sh[32 * 201];          // stride 201 (9 mod 32), conflict-free
    __shared__ unsigned int tw2_sh[5376];      // packed pairs [bank][kt2][64]
    __shared__ float tb_sh[192];
    __shared__ float Ash[2048];                // A_eff[m][c] for fused xs
    __shared__ float Bsh[32];                  // beta_eff

    int tid = threadIdx.x;
    int wg = blockIdx.x;
    int b = wg >> 3, chunk = wg & 7;
    int t0 = chunk * 128;

    // stage A_eff/beta + packed weights + biases (all independent)
    for (int i = tid; i < 2048; i += 384) Ash[i] = ws[A_OFF + i];
    if (tid < 32) Bsh[tid] = ws[BETA_OFF + tid];
    for (int idx = tid; idx < 5376; idx += 384) {
        int bank, rem;
        if (idx < 1536)      { bank = 0; rem = idx; }
        else if (idx < 3328) { bank = 1; rem = idx - 1536; }
        else                 { bank = 2; rem = idx - 3328; }
        int kt2 = rem >> 6, o = rem & 63;
        unsigned int lo = f2bf(ws[TWE_OFF + bank * 4096 + o * 64 + 2 * kt2]);
        unsigned int hi = f2bf(ws[TWE_OFF + bank * 4096 + o * 64 + 2 * kt2 + 1]);
        tw2_sh[idx] = lo | (hi << 16);
    }
    if (tid < 192) tb_sh[tid] = ws[TBE_OFF + tid];
    __syncthreads();                           // Ash/Bsh ready

    // fused xs: one thread per window position q (200 active)
    if (tid < 200) {
        int q = tid;
        int gt = t0 - 30 + q;
        float acc[32];
        if (gt >= 0 && gt < 1000) {
            const float* xp = x + b * 64000 + gt;
#pragma unroll
            for (int m = 0; m < 32; ++m) acc[m] = Bsh[m];
#pragma unroll 4
            for (int c = 0; c < 64; ++c) {
                float xv = xp[c * 1000];
#pragma unroll
                for (int m = 0; m < 32; ++m) acc[m] += Ash[m * 64 + c] * xv;
            }
        } else {
#pragma unroll
            for (int m = 0; m < 32; ++m) acc[m] = 0.f;
        }
#pragma unroll
        for (int m = 0; m < 32; ++m) xs_sh[m * 201 + q] = acc[m];
    }
    __syncthreads();

    unsigned short* xtg = (unsigned short*)(ws + XT_OFF);
    const int lane = tid & 63;
    const int wv   = tid >> 6;          // 0..5
    const int bank = wv % 3, thalf = wv / 3;
    const int o = lane, m = o >> 1;
    const int ch = bank * 64 + o;
    float bias = tb_sh[ch];
    int tbase = t0 + thalf * 64;
    unsigned short* op = &xtg[(size_t)(b * 192 + ch) * 1024 + tbase];
    const float* xp0 = &xs_sh[m * 201 + thalf * 64];

    if (bank == 0)      xt_task<48, 10>(xp0, &tw2_sh[0]    + o, bias, op, tbase);
    else if (bank == 1) xt_task<56, 5>( xp0, &tw2_sh[1536] + o, bias, op, tbase);
    else                xt_task<64, 0>( xp0, &tw2_sh[3328] + o, bias, op, tbase);
}

// ---------------------------------------------------------------------------
// K3b v2 (verified r12): Gram MFMA, 512 threads (8 waves), grid 256.
// ---------------------------------------------------------------------------
__global__ __launch_bounds__(512) void gram_kernel(float* __restrict__ ws)
{
    __shared__ __align__(16) unsigned short xsh[192 * 136];   // 52,224 B

    int tid = threadIdx.x;
    int b = blockIdx.x >> 1, h = blockIdx.x & 1;
    int nrows = h ? 192 : 128;

    const unsigned short* xtg = (const unsigned short*)(ws + XT_OFF);
    const unsigned short* gb = xtg + (size_t)b * 192 * 1024;

    floatx4 acc[3][2];
#pragma unroll
    for (int t = 0; t < 3; ++t)
#pragma unroll
        for (int sjl = 0; sjl < 2; ++sjl) acc[t][sjl] = (floatx4){0.f, 0.f, 0.f, 0.f};

    const int lane = tid & 63;
    const int wv8  = tid >> 6;          // 0..7
    const int wvr  = wv8 & 3;           // row quadrant
    const int sjb  = (wv8 >> 2) * 2;    // sj base: 0 or 2
    const int m15  = lane & 15;
    const int quad = lane >> 4;
    int nloads = nrows * 16;

    for (int t0 = 0; t0 < 1024; t0 += 128) {
        for (int idx = tid; idx < nloads; idx += 512) {
            int row = idx >> 4, c8 = idx & 15;
            *(short8*)&xsh[row * 136 + c8 * 8] =
                *(const short8*)&gb[(size_t)row * 1024 + t0 + c8 * 8];
        }
        __syncthreads();
        if (h == 0) {
#pragma unroll
            for (int k0 = 0; k0 < 128; k0 += 32) {
                short8 a0 = *(const short8*)&xsh[(      wvr * 16 + m15) * 136 + quad * 8 + k0];
                short8 a1 = *(const short8*)&xsh[( 64 + wvr * 16 + m15) * 136 + quad * 8 + k0];
#pragma unroll
                for (int sjl = 0; sjl < 2; ++sjl) {
                    int sj = sjb + sjl;
                    short8 b0 = *(const short8*)&xsh[(      sj * 16 + m15) * 136 + quad * 8 + k0];
                    short8 b1 = *(const short8*)&xsh[( 64 + sj * 16 + m15) * 136 + quad * 8 + k0];
                    acc[0][sjl] = __builtin_amdgcn_mfma_f32_16x16x32_bf16(a0, b0, acc[0][sjl], 0, 0, 0);
                    acc[1][sjl] = __builtin_amdgcn_mfma_f32_16x16x32_bf16(a1, b0, acc[1][sjl], 0, 0, 0);
                    acc[2][sjl] = __builtin_amdgcn_mfma_f32_16x16x32_bf16(a1, b1, acc[2][sjl], 0, 0, 0);
                }
            }
        } else {
#pragma unroll
            for (int k0 = 0; k0 < 128; k0 += 32) {
                short8 a2 = *(const short8*)&xsh[(128 + wvr * 16 + m15) * 136 + quad * 8 + k0];
#pragma unroll
                for (int sjl = 0; sjl < 2; ++sjl) {
                    int sj = sjb + sjl;
                    short8 b0 = *(const short8*)&xsh[(      sj * 16 + m15) * 136 + quad * 8 + k0];
                    short8 b1 = *(const short8*)&xsh[( 64 + sj * 16 + m15) * 136 + quad * 8 + k0];
                    short8 b2 = *(const short8*)&xsh[(128 + sj * 16 + m15) * 136 + quad * 8 + k0];
                    acc[0][sjl] = __builtin_amdgcn_mfma_f32_16x16x32_bf16(a2, b0, acc[0][sjl], 0, 0, 0);
                    acc[1][sjl] = __builtin_amdgcn_mfma_f32_16x16x32_bf16(a2, b1, acc[1][sjl], 0, 0, 0);
                    acc[2][sjl] = __builtin_amdgcn_mfma_f32_16x16x32_bf16(a2, b2, acc[2][sjl], 0, 0, 0);
                }
            }
        }
        __syncthreads();
    }

    const float sc = 1.0f / 999.0f;
#pragma unroll
    for (int t = 0; t < 3; ++t) {
        int tileid = h ? (3 + t) : t;
        float* xbp = ws + XBP_OFF + b * 24576 + tileid * 4096;
#pragma unroll
        for (int sjl = 0; sjl < 2; ++sjl)
#pragma unroll
            for (int r = 0; r < 4; ++r) {
                int i = wvr * 16 + quad * 4 + r;    // C/D: row = quad*4 + reg
                int j = (sjb + sjl) * 16 + m15;     //      col = lane & 15
                xbp[i * 64 + j] = acc[t][sjl][r] * sc;
            }
    }
}

// ---------------------------------------------------------------------------
// K3 (fallback, small ws): r8's fused conv+Gram kernel (verified).
// ---------------------------------------------------------------------------
__global__ __launch_bounds__(256, 3) void cov_kernel(float* __restrict__ ws)
{
    __shared__ float xs_sh[32 * 129];
    __shared__ __align__(16) unsigned short xt_sh[2 * 64 * 72];
    __shared__ unsigned short tw_sh[120 * 64];
    __shared__ float tb_sh[128];

    int tid = threadIdx.x;
    int wg = blockIdx.x;
    int b = wg / 6, tile = wg - b * 6;
    const int TIa[6] = {0, 1, 1, 2, 2, 2};
    const int TJa[6] = {0, 0, 1, 0, 1, 2};
    int I = TIa[tile], J = TJa[tile];
    const int fpad[3] = {20, 25, 30};
    const int fszp[3] = {48, 56, 64};
    int padI = fpad[I], szpI = fszp[I];
    int padJ = fpad[J], szpJ = fszp[J];
    bool diag = (I == J);

    int nI = szpI * 64;
    for (int idx = tid; idx < nI; idx += 256) {
        int kt = idx >> 6, o = idx & 63;
        tw_sh[idx] = f2bf(ws[TWE_OFF + I * 4096 + o * 64 + kt]);
    }
    if (!diag) {
        int nJ = szpJ * 64;
        for (int idx = tid; idx < nJ; idx += 256) {
            int kt = idx >> 6, o = idx & 63;
            tw_sh[nI + idx] = f2bf(ws[TWE_OFF + J * 4096 + o * 64 + kt]);
        }
    }
    if (tid < 64)        tb_sh[tid] = ws[TBE_OFF + I * 64 + tid];
    else if (tid < 128)  tb_sh[tid] = ws[TBE_OFF + J * 64 + (tid - 64)];

    floatx4 acc[4];
#pragma unroll
    for (int sj = 0; sj < 4; ++sj) acc[sj] = (floatx4){0.f, 0.f, 0.f, 0.f};

    const float* xsrow = ws + XS_OFF + b * 32000;
    unsigned short* xtI = xt_sh;
    unsigned short* xtJ = diag ? xt_sh : (xt_sh + 64 * 72);

    const int lane = tid & 63;
    const int wv   = tid >> 6;
    const int m15  = lane & 15;
    const int quad = lane >> 4;

    for (int t0 = 0; t0 < 1000; t0 += 64) {
        for (int idx = tid; idx < 4096; idx += 256) {
            int m = idx >> 7, q = idx & 127;
            int gt = t0 - 30 + q;
            xs_sh[m * 129 + q] = (gt >= 0 && gt < 1000) ? xsrow[m * 1000 + gt] : 0.f;
        }
        __syncthreads();
        for (int it = 0; it < 2; ++it) {
            int o   = lane;
            int grp = wv + it * 4;
            int tlb = grp * 8;
            int m   = o >> 1;
            float a[8];
            conv8_vals(a, &xs_sh[m * 129 + tlb + (30 - padI)], &tw_sh[o],
                       szpI, tb_sh[o]);
            short8 hv;
#pragma unroll
            for (int i = 0; i < 8; ++i) {
                int gt = t0 + tlb + i;
                hv[i] = (short)((gt < 1000) ? f2bf(a[i]) : 0);
            }
            *(short8*)&xtI[o * 72 + tlb] = hv;
            if (!diag) {
                conv8_vals(a, &xs_sh[m * 129 + tlb + (30 - padJ)], &tw_sh[nI + o],
                           szpJ, tb_sh[64 + o]);
#pragma unroll
                for (int i = 0; i < 8; ++i) {
                    int gt = t0 + tlb + i;
                    hv[i] = (short)((gt < 1000) ? f2bf(a[i]) : 0);
                }
                *(short8*)&xtJ[o * 72 + tlb] = hv;
            }
        }
        __syncthreads();
        const unsigned short* ap = &xtI[(wv * 16 + m15) * 72 + quad * 8];
#pragma unroll
        for (int k0 = 0; k0 < 64; k0 += 32) {
            short8 af = *(const short8*)(ap + k0);
#pragma unroll
            for (int sj = 0; sj < 4; ++sj) {
                short8 bf = *(const short8*)&xtJ[(sj * 16 + m15) * 72 + quad * 8 + k0];
                acc[sj] = __builtin_amdgcn_mfma_f32_16x16x32_bf16(af, bf, acc[sj],
                                                                  0, 0, 0);
            }
        }
        __syncthreads();
    }

    float* xbp = ws + XBP_OFF + b * 24576 + tile * 4096;
    const float sc = 1.0f / 999.0f;
#pragma unroll
    for (int sj = 0; sj < 4; ++sj)
#pragma unroll
        for (int r = 0; r < 4; ++r) {
            int i = wv * 16 + quad * 4 + r;
            int j = sj * 16 + m15;
            xbp[i * 64 + j] = acc[sj][r] * sc;
        }
}

// ---------------------------------------------------------------------------
// K4 v6 (verified r8, session-best; FINAL): 512 threads, trailing update
// sized to hipcc's VGPR cap (= 65536/block_size; launch-bounds 2nd arg and
// waves_per_eu both ineffective/harmful).  8x4 tiles, k-chunk 4 (~100 VGPR
// <= 128 cap, spill-free).  Ladder: 256->121us, 512->91us, 1024->127us.
// ---------------------------------------------------------------------------
#define LSTR 196
__device__ __forceinline__ int lidx(int i, int c) {
    return i * LSTR + ((((c >> 2) ^ ((i >> 3) & 7)) << 2) | (c & 3));
}

// 16x16 diag Cholesky in registers, lanes 0-15 of wave 0 (call under tid<16)
__device__ __forceinline__ void diag16(float* Lm, int j0, int i,
                                       float* invd_sh)
{
    float r[16];
#pragma unroll
    for (int c = 0; c < 16; ++c) r[c] = Lm[lidx(j0 + i, j0 + c)];
#pragma unroll
    for (int jj = 0; jj < 16; ++jj) {
        float d = __shfl(r[jj], jj);
        d = fmaxf(d, 1e-20f);
        float s = sqrtf(d);
        float inv = 1.0f / s;
        if (i == jj) { r[jj] = s; invd_sh[jj] = inv; }
        else if (i > jj) r[jj] *= inv;
#pragma unroll
        for (int cc = jj + 1; cc < 16; ++cc) {
            float vc = __shfl(r[jj], cc);
            if (i >= cc) r[cc] -= r[jj] * vc;
        }
    }
#pragma unroll
    for (int c = 0; c < 16; ++c)
        if (c <= i) Lm[lidx(j0 + i, j0 + c)] = r[c];
}

__global__ __launch_bounds__(512) void chol_kernel(const float* __restrict__ ws,
                                                   const float* __restrict__ fcw,
                                                   const float* __restrict__ fcb,
                                                   float* __restrict__ out)
{
    __shared__ __align__(16) float L[192 * LSTR];   // 150,528 B
    __shared__ float invd_sh[16];
    __shared__ float red[8][4];

    int b = blockIdx.x, tid = threadIdx.x;
    const float* Xb = ws + XBP_OFF + b * 24576;
    const int TIa[6] = {0, 1, 1, 2, 2, 2};
    const int TJa[6] = {0, 0, 1, 0, 1, 2};

    // load packed Gram tiles -> swizzled LDS (float4; c always mult of 4)
    for (int idx = tid; idx < 6144; idx += 512) {
        int fi = idx << 2;
        int t = fi >> 12, r = (fi >> 6) & 63, c = fi & 63;
        floatx4 val = *(const floatx4*)&Xb[fi];
        *(floatx4*)&L[lidx(TIa[t] * 64 + r, TJa[t] * 64 + c)] = val;
    }
    __syncthreads();

    // prologue: factor panel 0 diag
    if (tid < 16) diag16(L, 0, tid, invd_sh);
    __syncthreads();

    for (int p = 0; p <= 10; ++p) {
        int j0 = p * 16, j1 = j0 + 16;

        // --- B: TRSM, one row per thread, vectorized row access ---
        {
            int i = j1 + tid;
            if (i < 192) {
                floatx4 vv[4];
#pragma unroll
                for (int q = 0; q < 4; ++q)
                    vv[q] = *(floatx4*)&L[lidx(i, j0 + 4 * q)];
                float v[16];
#pragma unroll
                for (int k = 0; k < 16; ++k) v[k] = vv[k >> 2][k & 3];
#pragma unroll
                for (int k = 0; k < 16; ++k) {
                    float vk = v[k];
#pragma unroll
                    for (int p2 = 0; p2 < k; ++p2)
                        vk -= v[p2] * L[lidx(j0 + k, j0 + p2)];
                    v[k] = vk * invd_sh[k];
                }
#pragma unroll
                for (int k = 0; k < 16; ++k) vv[k >> 2][k & 3] = v[k];
#pragma unroll
                for (int q = 0; q < 4; ++q)
                    *(floatx4*)&L[lidx(i, j0 + 4 * q)] = vv[q];
            }
        }
        __syncthreads();

        // --- C: trailing rank-16 update + hidden diag factorization ---
        int RT = (192 - j1) >> 3;          // 8-row blocks
        int nt = RT * RT + RT;             // 8x4 lower-tri tiles: ti^2+ti+tj
        if (tid < 64) {
            // wave 0: update next diag 16x16 block (tiles t=0..5), then
            // factor it in-wave while waves 1-7 grind the remaining tiles.
            int r = tid & 15, cq = tid >> 4;
            floatx4 a4 = *(floatx4*)&L[lidx(j1 + r, j1 + cq * 4)];
#pragma unroll
            for (int k = 0; k < 16; ++k) {
                float pr = L[lidx(j1 + r, j0 + k)];
#pragma unroll
                for (int cc = 0; cc < 4; ++cc)
                    a4[cc] -= pr * L[lidx(j1 + cq * 4 + cc, j0 + k)];
            }
            *(floatx4*)&L[lidx(j1 + r, j1 + cq * 4)] = a4;
            if (tid < 16) diag16(L, j1, tid, invd_sh);
        } else {
            for (int t = 6 + (tid - 64); t < nt; t += 448) {
                int ti = (int)(sqrtf((float)t + 0.25f) - 0.5f);
                while (ti * ti + ti > t) --ti;
                while ((ti + 1) * (ti + 1) + (ti + 1) <= t) ++ti;
                int tj = t - ti * ti - ti;        // tj in [0, 2ti+2)
                int i0 = j1 + 8 * ti, c0 = j1 + 4 * tj;
                floatx4 a[8];
#pragma unroll
                for (int r = 0; r < 8; ++r)
                    a[r] = *(floatx4*)&L[lidx(i0 + r, c0)];
#pragma unroll 1
                for (int kk = 0; kk < 16; kk += 4) {
                    floatx4 pi[8], pc[4];
#pragma unroll
                    for (int r = 0; r < 8; ++r)
                        pi[r] = *(floatx4*)&L[lidx(i0 + r, j0 + kk)];
#pragma unroll
                    for (int c = 0; c < 4; ++c)
                        pc[c] = *(floatx4*)&L[lidx(c0 + c, j0 + kk)];
#pragma unroll
                    for (int k = 0; k < 4; ++k)
#pragma unroll
                        for (int r = 0; r < 8; ++r) {
                            float ar = pi[r][k];
#pragma unroll
                            for (int c = 0; c < 4; ++c)
                                a[r][c] -= ar * pc[c][k];
                        }
                }
#pragma unroll
                for (int r = 0; r < 8; ++r)
                    *(floatx4*)&L[lidx(i0 + r, c0)] = a[r];
            }
        }
        __syncthreads();
    }

    // fused tangent + FC (incremental tril index)
    float a0 = 0.f, a1 = 0.f, a2 = 0.f, a3 = 0.f;
    for (int d = tid; d < 192; d += 512) {
        float v = logf(fmaxf(L[lidx(d, d)], 1e-30f));
        a0 += v * fcw[d];
        a1 += v * fcw[18528 + d];
        a2 += v * fcw[2 * 18528 + d];
        a3 += v * fcw[3 * 18528 + d];
    }
    {
        int e = tid;
        float fe = (float)e;
        int r = (int)((1.0f + sqrtf(1.0f + 8.0f * fe)) * 0.5f);
        if (r < 1) r = 1;
        while (r * (r - 1) / 2 > e) --r;
        while ((r + 1) * r / 2 <= e) ++r;
        int c = e - r * (r - 1) / 2;
        for (; e < 18336; e += 512) {
            float v = L[lidx(r, c)];
            int dd = 192 + e;
            a0 += v * fcw[dd];
            a1 += v * fcw[18528 + dd];
            a2 += v * fcw[2 * 18528 + dd];
            a3 += v * fcw[3 * 18528 + dd];
            c += 512;
            while (c >= r) { c -= r; ++r; }
        }
    }
    for (int off = 32; off > 0; off >>= 1) {
        a0 += __shfl_down(a0, off);
        a1 += __shfl_down(a1, off);
        a2 += __shfl_down(a2, off);
        a3 += __shfl_down(a3, off);
    }
    int wv = tid >> 6, ln = tid & 63;
    if (ln == 0) { red[wv][0] = a0; red[wv][1] = a1; red[wv][2] = a2; red[wv][3] = a3; }
    __syncthreads();
    if (tid < 4) {
        float s = red[0][tid] + red[1][tid] + red[2][tid] + red[3][tid]
                + red[4][tid] + red[5][tid] + red[6][tid] + red[7][tid]
                + fcb[tid];
        out[b * 4 + tid] = s;
    }
}

// ---------------------------------------------------------------------------
extern "C" void kernel_launch(void* const* d_in, const int* in_sizes, int n_in,
                              void* d_out, int out_size, void* d_ws, size_t ws_size,
                              hipStream_t stream)
{
    float* ws = (float*)d_ws;

    prep_kernel<<<569, 256, 0, stream>>>(
        (const float*)d_in[1], (const float*)d_in[3], (const float*)d_in[5],
        (const float*)d_in[7], (const float*)d_in[9],
        (const float*)d_in[2], (const float*)d_in[4], (const float*)d_in[6],
        (const float*)d_in[8], (const float*)d_in[10],
        (const float*)d_in[11], (const float*)d_in[12], (const float*)d_in[13],
        (const float*)d_in[14],
        (const float*)d_in[15], (const float*)d_in[19], (const float*)d_in[23],
        (const float*)d_in[16], (const float*)d_in[20], (const float*)d_in[24],
        (const float*)d_in[17], (const float*)d_in[21], (const float*)d_in[25],
        (const float*)d_in[18], (const float*)d_in[22], (const float*)d_in[26], ws);
    if (ws_size >= WS_NEED) {
        // main path: xs fused into xt — no separate xs launch
        xt_kernel<<<1024, 384, 0, stream>>>((const float*)d_in[0], ws);
        gram_kernel<<<256, 512, 0, stream>>>(ws);     // v2: 8 waves/block
    } else {
        xs_kernel<<<500, 256, 0, stream>>>((const float*)d_in[0], ws);
        cov_kernel<<<768, 256, 0, stream>>>(ws);      // r8 fused fallback
    }
    chol_kernel<<<128, 512, 0, stream>>>(ws, (const float*)d_in[27],
                                         (const float*)d_in[28], (float*)d_out);
}